// Round 13
// baseline (111.710 us; speedup 1.0000x reference)
//
#include <hip/hip_runtime.h>

#define S 2048
#define E 1152
#define H 16
#define NSEG 4

typedef unsigned short u16;
typedef short bf16x8 __attribute__((ext_vector_type(8)));
typedef float f32x4 __attribute__((ext_vector_type(4)));

#define MFMA __builtin_amdgcn_mfma_f32_16x16x32_bf16

__device__ __forceinline__ u16 f2bf(float x) {
    unsigned u = __float_as_uint(x);
    u += 0x7fffu + ((u >> 16) & 1u);
    return (u16)(u >> 16);
}
__device__ __forceinline__ float bf2f(u16 h) {
    return __uint_as_float(((unsigned)h) << 16);
}
__device__ __forceinline__ bf16x8 ldb8(const u16* p) {
    return *(const bf16x8*)p;
}
__device__ __forceinline__ void gll16(const void* g, void* s) {
    __builtin_amdgcn_global_load_lds(
        (const __attribute__((address_space(1))) void*)g,
        (__attribute__((address_space(3))) void*)s,
        16, 0, 0);
}

// ---------------- fp32 -> bf16 conversion of hs + weights ----------------
__global__ __launch_bounds__(256)
void convert_inputs(const float* __restrict__ hs, const float* __restrict__ wq,
                    const float* __restrict__ wk, const float* __restrict__ wv,
                    const float* __restrict__ wo,
                    u16* __restrict__ hs_h, u16* __restrict__ wq_h,
                    u16* __restrict__ wk_h, u16* __restrict__ wv_h,
                    u16* __restrict__ wo_h)
{
    const size_t NH = (size_t)S * E, NW = (size_t)E * E;
    size_t i = ((size_t)blockIdx.x * 256 + threadIdx.x) * 4;
    const float* src; u16* dst; size_t off;
    if      (i < NH)          { src = hs; dst = hs_h; off = i; }
    else if (i < NH + NW)     { src = wq; dst = wq_h; off = i - NH; }
    else if (i < NH + 2*NW)   { src = wk; dst = wk_h; off = i - NH - NW; }
    else if (i < NH + 3*NW)   { src = wv; dst = wv_h; off = i - NH - 2*NW; }
    else if (i < NH + 4*NW)   { src = wo; dst = wo_h; off = i - NH - 3*NW; }
    else return;
    float4 v = *(const float4*)(src + off);
    ushort4 hv;
    hv.x = f2bf(v.x); hv.y = f2bf(v.y); hv.z = f2bf(v.z); hv.w = f2bf(v.w);
    *(ushort4*)(dst + off) = hv;
}

// ---------------- fused QKV projection: 128x128 tile, dbuf, T2 swizzle -----
// C[S,3456] = hs @ Wcat^T + bias. q,k written bf16 directly into the padded
// [h][s][96] attention layout (pre-RoPE); v written transposed into vt.
__global__ __launch_bounds__(256)
void gemm_qkv_f(const u16* __restrict__ hsb, const u16* __restrict__ wcat,
                const float* __restrict__ qb, const float* __restrict__ kb,
                const float* __restrict__ vb,
                u16* __restrict__ qbf, u16* __restrict__ kbf, u16* __restrict__ vt)
{
    __shared__ u16 As[2][128 * 64] __attribute__((aligned(16)));
    __shared__ u16 Bs[2][128 * 64] __attribute__((aligned(16)));
    const int tid = threadIdx.x;
    const int l = tid & 63, w = tid >> 6;
    const int wr = w >> 1, wc = w & 1;
    const int m0 = blockIdx.y * 128;
    const int n0 = blockIdx.x * 128;
    const int lr = l & 15, lk = (l >> 4) * 8;
    const int swz = (lr & 7) << 3;

    const int srow = tid >> 3;
    const int scol = ((tid & 7) ^ ((tid >> 3) & 7)) * 8;   // pre-swizzled source col
    const u16* ga = hsb  + (size_t)(m0 + srow) * E + scol;
    const u16* gb = wcat + (size_t)(n0 + srow) * E + scol;
    const int ldst = w * 512;

    f32x4 acc[4][4] = {};

#define QKV_STAGE(buf, kt)                                              \
    {                                                                   \
        const u16* _a = ga + (kt) * 64;                                 \
        const u16* _b = gb + (kt) * 64;                                 \
        _Pragma("unroll")                                               \
        for (int r = 0; r < 4; ++r) {                                   \
            gll16(_a + (size_t)r * 32 * E, &As[buf][ldst + r * 2048]);  \
            gll16(_b + (size_t)r * 32 * E, &Bs[buf][ldst + r * 2048]);  \
        }                                                               \
    }

    QKV_STAGE(0, 0);
    __syncthreads();
    int cur = 0;
    for (int kt = 0; kt < 18; ++kt) {
        if (kt + 1 < 18) QKV_STAGE(cur ^ 1, kt + 1);
        const u16* Ab = As[cur];
        const u16* Bb = Bs[cur];
#pragma unroll
        for (int kk = 0; kk < 2; ++kk) {
            const int csw = (kk * 32 + lk) ^ swz;
            bf16x8 af[4], bfr[4];
#pragma unroll
            for (int i = 0; i < 4; ++i) {
                af[i]  = ldb8(Ab + (wr * 64 + i * 16 + lr) * 64 + csw);
                bfr[i] = ldb8(Bb + (wc * 64 + i * 16 + lr) * 64 + csw);
            }
#pragma unroll
            for (int i = 0; i < 4; ++i)
#pragma unroll
                for (int j = 0; j < 4; ++j)
                    acc[i][j] = MFMA(af[i], bfr[j], acc[i][j], 0, 0, 0);
        }
        __syncthreads();
        cur ^= 1;
    }

    const int zb = n0 / E;
    const int ncol = n0 - zb * E;
    const float* bias = (zb == 0) ? qb : (zb == 1) ? kb : vb;
    u16* qk = (zb == 0) ? qbf : kbf;
#pragma unroll
    for (int i = 0; i < 4; ++i) {
        int rbase = m0 + wr * 64 + i * 16 + (l >> 4) * 4;
#pragma unroll
        for (int j = 0; j < 4; ++j) {
            int cc = ncol + wc * 64 + j * 16 + lr;
            int hh = cc / 72, d = cc - hh * 72;
#pragma unroll
            for (int r = 0; r < 4; ++r) {
                float val = acc[i][j][r] + bias[cc];
                if (zb < 2) {
                    qk[((size_t)hh * S + rbase + r) * 96 + d] = f2bf(val);
                } else {
                    vt[((size_t)hh * 80 + d) * S + rbase + r] = f2bf(val);
                }
            }
        }
    }
}

// ---------------- RoPE: in-place bf16 RMW on qbf/kbf + pad zeroing ---------
// q additionally scaled by 72^-0.5 * log2(e) so attention can use exp2.
__global__ __launch_bounds__(256)
void rope_convert(u16* __restrict__ qbf, u16* __restrict__ kbf,
                  const float* __restrict__ cosp, const float* __restrict__ sinp,
                  u16* __restrict__ vt)
{
    int idx = blockIdx.x * 256 + threadIdx.x;
    if (idx >= S * H * 36) return;
    int d = idx % 36;
    int h = (idx / 36) % H;
    int s = idx / (36 * H);
    float c = cosp[s * 72 + d], sn = sinp[s * 72 + d];
    size_t base = ((size_t)h * S + s) * 96;
    float q0 = bf2f(qbf[base + d]), q1 = bf2f(qbf[base + d + 36]);
    float k0 = bf2f(kbf[base + d]), k1 = bf2f(kbf[base + d + 36]);
    const float qs = 0.17002330685923512f;   // 72^-0.5 * log2(e)
    qbf[base + d]      = f2bf((q0 * c - q1 * sn) * qs);
    qbf[base + d + 36] = f2bf((q1 * c + q0 * sn) * qs);
    kbf[base + d]      = f2bf(k0 * c - k1 * sn);
    kbf[base + d + 36] = f2bf(k1 * c + k0 * sn);
    if (d < 24) { qbf[base + 72 + d] = 0; kbf[base + 72 + d] = 0; }
    if (d < 8)  { vt[((size_t)h * 80 + 72 + d) * S + s] = 0; }
}

// ---------------- flash attention helpers ---------------------------------
__device__ __forceinline__ void loadK(bf16x8 (&kf)[12], const u16* kp) {
#pragma unroll
    for (int nt = 0; nt < 4; ++nt)
#pragma unroll
        for (int ks = 0; ks < 3; ++ks)
            kf[nt * 3 + ks] = ldb8(kp + nt * 16 * 96 + ks * 32);
}
__device__ __forceinline__ void loadV(bf16x8 (&vf)[10], const u16* vp) {
#pragma unroll
    for (int nt = 0; nt < 5; ++nt)
#pragma unroll
        for (int ks = 0; ks < 2; ++ks)
            vf[nt * 2 + ks] = ldb8(vp + (size_t)nt * 16 * S + ks * 32);
}
__device__ __forceinline__ void qkStep(f32x4 (&sc)[4], const bf16x8 (&qfr)[3],
                                       const bf16x8 (&kf)[12]) {
#pragma unroll
    for (int nt = 0; nt < 4; ++nt) {
        sc[nt] = f32x4{0.f, 0.f, 0.f, 0.f};
#pragma unroll
        for (int ks = 0; ks < 3; ++ks)
            sc[nt] = MFMA(qfr[ks], kf[nt * 3 + ks], sc[nt], 0, 0, 0);
    }
}
// p = exp2(s) (log2e pre-folded into q). P packed to bf16 by TRUNCATION;
// lsum accumulates the truncated value so the bias cancels in O = PV/lsum.
__device__ __forceinline__ void pvBody(const f32x4 (&sc)[4], float (&lsum)[4],
                                       const bf16x8 (&vf)[10], f32x4 (&oacc)[5],
                                       u16 (*pl)[72], int l) {
    const int lr = l & 15, g = l >> 4;
#pragma unroll
    for (int nt = 0; nt < 4; ++nt)
#pragma unroll
        for (int r = 0; r < 4; ++r) {
            float p = __builtin_amdgcn_exp2f(sc[nt][r]);
            unsigned pu = __float_as_uint(p) & 0xffff0000u;
            lsum[r] += __uint_as_float(pu);
            pl[g * 4 + r][lr + nt * 16] = (u16)(pu >> 16);
        }
    const int koff = g * 8;
#pragma unroll
    for (int ks = 0; ks < 2; ++ks) {
        bf16x8 pf = ldb8(&pl[lr][ks * 32 + koff]);
#pragma unroll
        for (int nt = 0; nt < 5; ++nt)
            oacc[nt] = MFMA(pf, vf[nt * 2 + ks], oacc[nt], 0, 0, 0);
    }
}

// ---------------- flash attention, bf16 MFMA, K and V double-buffered ------
__global__ __launch_bounds__(256, 2)
void attn_mfma(const u16* __restrict__ qbf, const u16* __restrict__ kbf,
               const u16* __restrict__ vt, u16* __restrict__ ao,
               const int* __restrict__ cu)
{
    __shared__ u16 p_lds[4][16][72] __attribute__((aligned(16)));
    const int b = blockIdx.x;
    const int sid = (b & 7) * 64 + (b >> 3);   // XCD-chunked swizzle (512 % 8 == 0)
    const int h = sid >> 5;
    const int q0 = (sid & 31) * 64;
    const int l = threadIdx.x & 63, w = threadIdx.x >> 6;

    int kstart = 0, kend = S;
#pragma unroll
    for (int i = 0; i < NSEG; ++i) {
        int a = cu[i], b2 = cu[i + 1];
        if (q0 >= a && q0 < b2) { kstart = a; kend = b2; }
    }

    const int lr = l & 15;
    const int koff = (l >> 4) * 8;
    const u16* kbase = kbf + ((size_t)h * S + lr) * 96 + koff;
    const u16* vbase = vt + ((size_t)h * 80 + lr) * S + koff;

    bf16x8 qfr[3];
#pragma unroll
    for (int ks = 0; ks < 3; ++ks)
        qfr[ks] = ldb8(qbf + ((size_t)h * S + q0 + w * 16 + lr) * 96 + ks * 32 + koff);

    f32x4 oacc[5] = {};
    float lsum[4] = {0.f, 0.f, 0.f, 0.f};

    bf16x8 kfA[12], kfB[12], vfA[10], vfB[10];
    loadK(kfA, kbase + (size_t)kstart * 96);
    loadV(vfA, vbase + kstart);

    const int nch = (kend - kstart) >> 6;
    for (int c = 0; c < nch; c += 2) {
        const int kv0 = kstart + c * 64;
        f32x4 sc[4];
        qkStep(sc, qfr, kfA);
        if (c + 1 < nch) {
            loadK(kfB, kbase + (size_t)(kv0 + 64) * 96);
            loadV(vfB, vbase + kv0 + 64);
        }
        pvBody(sc, lsum, vfA, oacc, p_lds[w], l);
        if (c + 1 < nch) {
            qkStep(sc, qfr, kfB);
            if (c + 2 < nch) {
                loadK(kfA, kbase + (size_t)(kv0 + 128) * 96);
                loadV(vfA, vbase + kv0 + 128);
            }
            pvBody(sc, lsum, vfB, oacc, p_lds[w], l);
        }
    }

    // epilogue: row-sum reduce (16-lane), normalize, write bf16
#pragma unroll
    for (int r = 0; r < 4; ++r) {
        float t = lsum[r];
        t += __shfl_xor(t, 1);
        t += __shfl_xor(t, 2);
        t += __shfl_xor(t, 4);
        t += __shfl_xor(t, 8);
        float inv = 1.0f / t;
        int srow = q0 + w * 16 + (l >> 4) * 4 + r;
#pragma unroll
        for (int nt = 0; nt < 5; ++nt) {
            int d = nt * 16 + lr;
            if (d < 72)
                ao[(size_t)srow * E + h * 72 + d] = f2bf(oacc[nt][r] * inv);
        }
    }
}

// ---------------- O projection: plain bf16 GEMM, 64x128 tile, dbuf+swz -----
__global__ __launch_bounds__(256)
void gemm_o(const u16* __restrict__ ao, const u16* __restrict__ wo,
            const float* __restrict__ bias, float* __restrict__ out)
{
    __shared__ u16 As[2][64 * 64]  __attribute__((aligned(16)));
    __shared__ u16 Bs[2][128 * 64] __attribute__((aligned(16)));
    const int tid = threadIdx.x;
    const int l = tid & 63, w = tid >> 6;
    const int wr = w >> 1, wc = w & 1;          // wave tile 32(m) x 64(n)
    const int bid = blockIdx.x;
    const int sid = (bid & 7) * 36 + (bid >> 3);
    const int m0 = (sid / 9) * 64;
    const int n0 = (sid % 9) * 128;
    const int lr = l & 15, lk = (l >> 4) * 8;
    const int swz = (lr & 7) << 3;

    const int srow = tid >> 3;
    const int scol = ((tid & 7) ^ ((tid >> 3) & 7)) * 8;
    const u16* ga = ao + (size_t)(m0 + srow) * E + scol;
    const u16* gb = wo + (size_t)(n0 + srow) * E + scol;
    const int ldst = w * 512;

    f32x4 acc[2][4] = {};

#define O_STAGE(buf, kt)                                                \
    {                                                                   \
        const u16* _a = ga + (kt) * 64;                                 \
        const u16* _b = gb + (kt) * 64;                                 \
        _Pragma("unroll")                                               \
        for (int r = 0; r < 2; ++r)                                     \
            gll16(_a + (size_t)r * 32 * E, &As[buf][ldst + r * 2048]);  \
        _Pragma("unroll")                                               \
        for (int r = 0; r < 4; ++r)                                     \
            gll16(_b + (size_t)r * 32 * E, &Bs[buf][ldst + r * 2048]);  \
    }

    O_STAGE(0, 0);
    __syncthreads();
    int cur = 0;
    for (int kt = 0; kt < 18; ++kt) {
        if (kt + 1 < 18) O_STAGE(cur ^ 1, kt + 1);
        const u16* Ab = As[cur];
        const u16* Bb = Bs[cur];
#pragma unroll
        for (int kk = 0; kk < 2; ++kk) {
            const int csw = (kk * 32 + lk) ^ swz;
            bf16x8 fa[2], fb[4];
#pragma unroll
            for (int i = 0; i < 2; ++i)
                fa[i] = ldb8(Ab + (wr * 32 + i * 16 + lr) * 64 + csw);
#pragma unroll
            for (int j = 0; j < 4; ++j)
                fb[j] = ldb8(Bb + (wc * 64 + j * 16 + lr) * 64 + csw);
#pragma unroll
            for (int i = 0; i < 2; ++i)
#pragma unroll
                for (int j = 0; j < 4; ++j)
                    acc[i][j] = MFMA(fa[i], fb[j], acc[i][j], 0, 0, 0);
        }
        __syncthreads();
        cur ^= 1;
    }
#pragma unroll
    for (int i = 0; i < 2; ++i) {
        int rbase = m0 + wr * 32 + i * 16 + (l >> 4) * 4;
#pragma unroll
        for (int j = 0; j < 4; ++j) {
            int cc = n0 + wc * 64 + j * 16 + lr;
#pragma unroll
            for (int r = 0; r < 4; ++r)
                out[(size_t)(rbase + r) * E + cc] = acc[i][j][r] + bias[cc];
        }
    }
}

extern "C" void kernel_launch(void* const* d_in, const int* in_sizes, int n_in,
                              void* d_out, int out_size, void* d_ws, size_t ws_size,
                              hipStream_t stream)
{
    const float* hs   = (const float*)d_in[0];
    const float* q_w  = (const float*)d_in[1];
    const float* q_b  = (const float*)d_in[2];
    const float* k_w  = (const float*)d_in[3];
    const float* k_b  = (const float*)d_in[4];
    const float* v_w  = (const float*)d_in[5];
    const float* v_b  = (const float*)d_in[6];
    const float* o_w  = (const float*)d_in[7];
    const float* o_b  = (const float*)d_in[8];
    const float* cosp = (const float*)d_in[9];
    const float* sinp = (const float*)d_in[10];
    const int*   cu   = (const int*)d_in[11];
    float* out = (float*)d_out;

    char* p = (char*)d_ws;
    u16* hs_h = (u16*)p; p += (size_t)S * E * 2;
    u16* wq_h = (u16*)p; p += (size_t)E * E * 2;   // wq/wk/wv contiguous = Wcat[3456][1152]
    u16* wk_h = (u16*)p; p += (size_t)E * E * 2;
    u16* wv_h = (u16*)p; p += (size_t)E * E * 2;
    u16* wo_h = (u16*)p; p += (size_t)E * E * 2;
    u16* qbf = (u16*)p; p += (size_t)H * S * 96 * 2;
    u16* kbf = (u16*)p; p += (size_t)H * S * 96 * 2;
    u16* vt  = (u16*)p; p += (size_t)H * 80 * S * 2;
    u16* ao  = (u16*)p; p += (size_t)S * E * 2;

    convert_inputs<<<7488, 256, 0, stream>>>(hs, q_w, k_w, v_w, o_w,
                                             hs_h, wq_h, wk_h, wv_h, wo_h);
    dim3 gq(27, 16);
    gemm_qkv_f<<<gq, 256, 0, stream>>>(hs_h, wq_h, q_b, k_b, v_b, qbf, kbf, vt);
    rope_convert<<<(S * H * 36) / 256, 256, 0, stream>>>(qbf, kbf, cosp, sinp, vt);
    attn_mfma<<<512, 256, 0, stream>>>(qbf, kbf, vt, ao, cu);
    gemm_o<<<288, 256, 0, stream>>>(ao, wo_h, o_b, out);
}

// Round 14
// 94.900 us; speedup vs baseline: 1.1771x; 1.1771x over previous
//
#include <hip/hip_runtime.h>

#define S 2048
#define E 1152
#define H 16
#define NSEG 4

typedef unsigned short u16;
typedef short bf16x8 __attribute__((ext_vector_type(8)));
typedef float f32x4 __attribute__((ext_vector_type(4)));

#define MFMA __builtin_amdgcn_mfma_f32_16x16x32_bf16

__device__ __forceinline__ u16 f2bf(float x) {
    unsigned u = __float_as_uint(x);
    u += 0x7fffu + ((u >> 16) & 1u);
    return (u16)(u >> 16);
}
__device__ __forceinline__ float bf2f(u16 h) {
    return __uint_as_float(((unsigned)h) << 16);
}
__device__ __forceinline__ bf16x8 ldb8(const u16* p) {
    return *(const bf16x8*)p;
}
__device__ __forceinline__ void gll16(const void* g, void* s) {
    __builtin_amdgcn_global_load_lds(
        (const __attribute__((address_space(1))) void*)g,
        (__attribute__((address_space(3))) void*)s,
        16, 0, 0);
}

// ---------------- fp32 -> bf16 conversion of hs + weights ----------------
__global__ __launch_bounds__(256)
void convert_inputs(const float* __restrict__ hs, const float* __restrict__ wq,
                    const float* __restrict__ wk, const float* __restrict__ wv,
                    const float* __restrict__ wo,
                    u16* __restrict__ hs_h, u16* __restrict__ wq_h,
                    u16* __restrict__ wk_h, u16* __restrict__ wv_h,
                    u16* __restrict__ wo_h)
{
    const size_t NH = (size_t)S * E, NW = (size_t)E * E;
    size_t i = ((size_t)blockIdx.x * 256 + threadIdx.x) * 4;
    const float* src; u16* dst; size_t off;
    if      (i < NH)          { src = hs; dst = hs_h; off = i; }
    else if (i < NH + NW)     { src = wq; dst = wq_h; off = i - NH; }
    else if (i < NH + 2*NW)   { src = wk; dst = wk_h; off = i - NH - NW; }
    else if (i < NH + 3*NW)   { src = wv; dst = wv_h; off = i - NH - 2*NW; }
    else if (i < NH + 4*NW)   { src = wo; dst = wo_h; off = i - NH - 3*NW; }
    else return;
    float4 v = *(const float4*)(src + off);
    ushort4 hv;
    hv.x = f2bf(v.x); hv.y = f2bf(v.y); hv.z = f2bf(v.z); hv.w = f2bf(v.w);
    *(ushort4*)(dst + off) = hv;
}

// ---------------- fused QKV projection: 128x128 tile, dbuf, T2 swizzle -----
// C[S,3456] = hs @ Wcat^T + bias. q,k written bf16 directly into the padded
// [h][s][96] attention layout (pre-RoPE); v written transposed into vt.
__global__ __launch_bounds__(256)
void gemm_qkv_f(const u16* __restrict__ hsb, const u16* __restrict__ wcat,
                const float* __restrict__ qb, const float* __restrict__ kb,
                const float* __restrict__ vb,
                u16* __restrict__ qbf, u16* __restrict__ kbf, u16* __restrict__ vt)
{
    __shared__ u16 As[2][128 * 64] __attribute__((aligned(16)));
    __shared__ u16 Bs[2][128 * 64] __attribute__((aligned(16)));
    const int tid = threadIdx.x;
    const int l = tid & 63, w = tid >> 6;
    const int wr = w >> 1, wc = w & 1;
    const int m0 = blockIdx.y * 128;
    const int n0 = blockIdx.x * 128;
    const int lr = l & 15, lk = (l >> 4) * 8;
    const int swz = (lr & 7) << 3;

    const int srow = tid >> 3;
    const int scol = ((tid & 7) ^ ((tid >> 3) & 7)) * 8;   // pre-swizzled source col
    const u16* ga = hsb  + (size_t)(m0 + srow) * E + scol;
    const u16* gb = wcat + (size_t)(n0 + srow) * E + scol;
    const int ldst = w * 512;

    f32x4 acc[4][4] = {};

#define QKV_STAGE(buf, kt)                                              \
    {                                                                   \
        const u16* _a = ga + (kt) * 64;                                 \
        const u16* _b = gb + (kt) * 64;                                 \
        _Pragma("unroll")                                               \
        for (int r = 0; r < 4; ++r) {                                   \
            gll16(_a + (size_t)r * 32 * E, &As[buf][ldst + r * 2048]);  \
            gll16(_b + (size_t)r * 32 * E, &Bs[buf][ldst + r * 2048]);  \
        }                                                               \
    }

    QKV_STAGE(0, 0);
    __syncthreads();
    int cur = 0;
    for (int kt = 0; kt < 18; ++kt) {
        if (kt + 1 < 18) QKV_STAGE(cur ^ 1, kt + 1);
        const u16* Ab = As[cur];
        const u16* Bb = Bs[cur];
#pragma unroll
        for (int kk = 0; kk < 2; ++kk) {
            const int csw = (kk * 32 + lk) ^ swz;
            bf16x8 af[4], bfr[4];
#pragma unroll
            for (int i = 0; i < 4; ++i) {
                af[i]  = ldb8(Ab + (wr * 64 + i * 16 + lr) * 64 + csw);
                bfr[i] = ldb8(Bb + (wc * 64 + i * 16 + lr) * 64 + csw);
            }
#pragma unroll
            for (int i = 0; i < 4; ++i)
#pragma unroll
                for (int j = 0; j < 4; ++j)
                    acc[i][j] = MFMA(af[i], bfr[j], acc[i][j], 0, 0, 0);
        }
        __syncthreads();
        cur ^= 1;
    }

    const int zb = n0 / E;
    const int ncol = n0 - zb * E;
    const float* bias = (zb == 0) ? qb : (zb == 1) ? kb : vb;
    u16* qk = (zb == 0) ? qbf : kbf;
#pragma unroll
    for (int i = 0; i < 4; ++i) {
        int rbase = m0 + wr * 64 + i * 16 + (l >> 4) * 4;
#pragma unroll
        for (int j = 0; j < 4; ++j) {
            int cc = ncol + wc * 64 + j * 16 + lr;
            int hh = cc / 72, d = cc - hh * 72;
#pragma unroll
            for (int r = 0; r < 4; ++r) {
                float val = acc[i][j][r] + bias[cc];
                if (zb < 2) {
                    qk[((size_t)hh * S + rbase + r) * 96 + d] = f2bf(val);
                } else {
                    vt[((size_t)hh * 80 + d) * S + rbase + r] = f2bf(val);
                }
            }
        }
    }
}

// ---------------- RoPE: in-place bf16 RMW on qbf/kbf + pad zeroing ---------
// q additionally scaled by 72^-0.5 * log2(e) so attention can use exp2.
__global__ __launch_bounds__(256)
void rope_convert(u16* __restrict__ qbf, u16* __restrict__ kbf,
                  const float* __restrict__ cosp, const float* __restrict__ sinp,
                  u16* __restrict__ vt)
{
    int idx = blockIdx.x * 256 + threadIdx.x;
    if (idx >= S * H * 36) return;
    int d = idx % 36;
    int h = (idx / 36) % H;
    int s = idx / (36 * H);
    float c = cosp[s * 72 + d], sn = sinp[s * 72 + d];
    size_t base = ((size_t)h * S + s) * 96;
    float q0 = bf2f(qbf[base + d]), q1 = bf2f(qbf[base + d + 36]);
    float k0 = bf2f(kbf[base + d]), k1 = bf2f(kbf[base + d + 36]);
    const float qs = 0.17002330685923512f;   // 72^-0.5 * log2(e)
    qbf[base + d]      = f2bf((q0 * c - q1 * sn) * qs);
    qbf[base + d + 36] = f2bf((q1 * c + q0 * sn) * qs);
    kbf[base + d]      = f2bf(k0 * c - k1 * sn);
    kbf[base + d + 36] = f2bf(k1 * c + k0 * sn);
    if (d < 24) { qbf[base + 72 + d] = 0; kbf[base + 72 + d] = 0; }
    if (d < 8)  { vt[((size_t)h * 80 + 72 + d) * S + s] = 0; }
}

// ---------------- flash attention: LDS-staged K/V shared across 4 waves ----
// Block = 4 waves, 64 q-rows; kv chunks of 64 double-buffered in LDS via
// global_load_lds (linear dest + pre-swizzled per-lane source, rule #21).
// K tile [64][96] u16: slot s<8 <-> granule s^(row&7) (2-way, free);
// slots 8-11 <-> 8+((s&3)^(row&3)) (4-way on 1/3 of reads). V [80][64]:
// slot ^ (d&7) (free). One __syncthreads per chunk (drain after compute).
__global__ __launch_bounds__(256)
void attn_mfma(const u16* __restrict__ qbf, const u16* __restrict__ kbf,
               const u16* __restrict__ vt, u16* __restrict__ ao,
               const int* __restrict__ cu)
{
    __shared__ u16 Kl[2][64 * 96] __attribute__((aligned(16)));
    __shared__ u16 Vl[2][80 * 64] __attribute__((aligned(16)));
    __shared__ u16 p_lds[4][16][72] __attribute__((aligned(16)));

    const int b = blockIdx.x;
    const int sid = (b & 7) * 64 + (b >> 3);   // XCD-chunked swizzle
    const int h = sid >> 5;
    const int q0 = (sid & 31) * 64;
    const int l = threadIdx.x & 63, w = threadIdx.x >> 6;
    const int lr = l & 15, g = l >> 4;
    const int koff = g * 8;

    int kstart = 0, kend = S;
#pragma unroll
    for (int i = 0; i < NSEG; ++i) {
        int a = cu[i], b2 = cu[i + 1];
        if (q0 >= a && q0 < b2) { kstart = a; kend = b2; }
    }

    bf16x8 qfr[3];
#pragma unroll
    for (int ks = 0; ks < 3; ++ks)
        qfr[ks] = ldb8(qbf + ((size_t)h * S + q0 + w * 16 + lr) * 96 + ks * 32 + koff);

    f32x4 oacc[5] = {};
    float lsum[4] = {0.f, 0.f, 0.f, 0.f};

    // stage one 64-kv chunk: 22 wave-units of 1024B (12 K + 10 V)
#define ATTN_STAGE(buf, kv0_)                                                \
    {                                                                        \
        _Pragma("unroll")                                                    \
        for (int uu = 0; uu < 6; ++uu) {                                     \
            const int u = w + uu * 4;                                        \
            if (u < 22) {                                                    \
                const int f = u << 10;                                       \
                if (u < 12) {                                                \
                    int fb = f + l * 16;                                     \
                    int row = fb / 192;                                      \
                    int slot = (fb % 192) >> 4;                              \
                    int gs = slot < 8 ? (slot ^ (row & 7))                   \
                                      : (8 + ((slot & 3) ^ (row & 3)));      \
                    gll16(kbf + ((size_t)h * S + (kv0_) + row) * 96 + gs * 8,\
                          (char*)&Kl[buf][0] + f);                           \
                } else {                                                     \
                    int fb = (f - 12288) + l * 16;                           \
                    int d = fb >> 7;                                         \
                    int slot = (fb & 127) >> 4;                              \
                    int gs = slot ^ (d & 7);                                 \
                    gll16(vt + ((size_t)h * 80 + d) * S + (kv0_) + gs * 8,   \
                          (char*)&Vl[buf][0] + (f - 12288));                 \
                }                                                            \
            }                                                                \
        }                                                                    \
    }

#define ATTN_COMP(buf)                                                       \
    {                                                                        \
        f32x4 sc[4];                                                         \
        _Pragma("unroll")                                                    \
        for (int nt = 0; nt < 4; ++nt) {                                     \
            sc[nt] = f32x4{0.f, 0.f, 0.f, 0.f};                              \
            const int row = nt * 16 + lr;                                    \
            _Pragma("unroll")                                                \
            for (int ks = 0; ks < 3; ++ks) {                                 \
                const int G = ks * 4 + g;                                    \
                const int gsw = G < 8 ? (G ^ (lr & 7))                       \
                                      : (8 + ((G & 3) ^ (lr & 3)));          \
                bf16x8 kfr = ldb8(&Kl[buf][row * 96 + gsw * 8]);             \
                sc[nt] = MFMA(qfr[ks], kfr, sc[nt], 0, 0, 0);                \
            }                                                                \
        }                                                                    \
        _Pragma("unroll")                                                    \
        for (int nt = 0; nt < 4; ++nt)                                       \
            _Pragma("unroll")                                                \
            for (int r = 0; r < 4; ++r) {                                    \
                float pv = __builtin_amdgcn_exp2f(sc[nt][r]);                \
                unsigned pu = __float_as_uint(pv) & 0xffff0000u;             \
                lsum[r] += __uint_as_float(pu);                              \
                p_lds[w][g * 4 + r][lr + nt * 16] = (u16)(pu >> 16);         \
            }                                                                \
        _Pragma("unroll")                                                    \
        for (int ks = 0; ks < 2; ++ks) {                                     \
            bf16x8 pf = ldb8(&p_lds[w][lr][ks * 32 + koff]);                 \
            _Pragma("unroll")                                                \
            for (int nt = 0; nt < 5; ++nt) {                                 \
                const int vrow = nt * 16 + lr;                               \
                const int vsl = (ks * 4 + g) ^ (lr & 7);                     \
                bf16x8 vf = ldb8(&Vl[buf][vrow * 64 + vsl * 8]);             \
                oacc[nt] = MFMA(pf, vf, oacc[nt], 0, 0, 0);                  \
            }                                                                \
        }                                                                    \
    }

    const int nch = (kend - kstart) >> 6;
    ATTN_STAGE(0, kstart);
    __syncthreads();
    int cur = 0;
    for (int c = 0; c < nch; ++c) {
        if (c + 1 < nch) ATTN_STAGE(cur ^ 1, kstart + (c + 1) * 64);
        ATTN_COMP(cur);
        __syncthreads();
        cur ^= 1;
    }

    // epilogue: row-sum reduce (16-lane), normalize, write bf16
#pragma unroll
    for (int r = 0; r < 4; ++r) {
        float t = lsum[r];
        t += __shfl_xor(t, 1);
        t += __shfl_xor(t, 2);
        t += __shfl_xor(t, 4);
        t += __shfl_xor(t, 8);
        float inv = 1.0f / t;
        int srow = q0 + w * 16 + g * 4 + r;
#pragma unroll
        for (int nt = 0; nt < 5; ++nt) {
            int d = nt * 16 + lr;
            if (d < 72)
                ao[(size_t)srow * E + h * 72 + d] = f2bf(oacc[nt][r] * inv);
        }
    }
}

// ---------------- O projection: plain bf16 GEMM, 64x128 tile, dbuf+swz -----
__global__ __launch_bounds__(256)
void gemm_o(const u16* __restrict__ ao, const u16* __restrict__ wo,
            const float* __restrict__ bias, float* __restrict__ out)
{
    __shared__ u16 As[2][64 * 64]  __attribute__((aligned(16)));
    __shared__ u16 Bs[2][128 * 64] __attribute__((aligned(16)));
    const int tid = threadIdx.x;
    const int l = tid & 63, w = tid >> 6;
    const int wr = w >> 1, wc = w & 1;          // wave tile 32(m) x 64(n)
    const int bid = blockIdx.x;
    const int sid = (bid & 7) * 36 + (bid >> 3);
    const int m0 = (sid / 9) * 64;
    const int n0 = (sid % 9) * 128;
    const int lr = l & 15, lk = (l >> 4) * 8;
    const int swz = (lr & 7) << 3;

    const int srow = tid >> 3;
    const int scol = ((tid & 7) ^ ((tid >> 3) & 7)) * 8;
    const u16* ga = ao + (size_t)(m0 + srow) * E + scol;
    const u16* gb = wo + (size_t)(n0 + srow) * E + scol;
    const int ldst = w * 512;

    f32x4 acc[2][4] = {};

#define O_STAGE(buf, kt)                                                \
    {                                                                   \
        const u16* _a = ga + (kt) * 64;                                 \
        const u16* _b = gb + (kt) * 64;                                 \
        _Pragma("unroll")                                               \
        for (int r = 0; r < 2; ++r)                                     \
            gll16(_a + (size_t)r * 32 * E, &As[buf][ldst + r * 2048]);  \
        _Pragma("unroll")                                               \
        for (int r = 0; r < 4; ++r)                                     \
            gll16(_b + (size_t)r * 32 * E, &Bs[buf][ldst + r * 2048]);  \
    }

    O_STAGE(0, 0);
    __syncthreads();
    int cur = 0;
    for (int kt = 0; kt < 18; ++kt) {
        if (kt + 1 < 18) O_STAGE(cur ^ 1, kt + 1);
        const u16* Ab = As[cur];
        const u16* Bb = Bs[cur];
#pragma unroll
        for (int kk = 0; kk < 2; ++kk) {
            const int csw = (kk * 32 + lk) ^ swz;
            bf16x8 fa[2], fb[4];
#pragma unroll
            for (int i = 0; i < 2; ++i)
                fa[i] = ldb8(Ab + (wr * 32 + i * 16 + lr) * 64 + csw);
#pragma unroll
            for (int j = 0; j < 4; ++j)
                fb[j] = ldb8(Bb + (wc * 64 + j * 16 + lr) * 64 + csw);
#pragma unroll
            for (int i = 0; i < 2; ++i)
#pragma unroll
                for (int j = 0; j < 4; ++j)
                    acc[i][j] = MFMA(fa[i], fb[j], acc[i][j], 0, 0, 0);
        }
        __syncthreads();
        cur ^= 1;
    }
#pragma unroll
    for (int i = 0; i < 2; ++i) {
        int rbase = m0 + wr * 32 + i * 16 + (l >> 4) * 4;
#pragma unroll
        for (int j = 0; j < 4; ++j) {
            int cc = n0 + wc * 64 + j * 16 + lr;
#pragma unroll
            for (int r = 0; r < 4; ++r)
                out[(size_t)(rbase + r) * E + cc] = acc[i][j][r] + bias[cc];
        }
    }
}

extern "C" void kernel_launch(void* const* d_in, const int* in_sizes, int n_in,
                              void* d_out, int out_size, void* d_ws, size_t ws_size,
                              hipStream_t stream)
{
    const float* hs   = (const float*)d_in[0];
    const float* q_w  = (const float*)d_in[1];
    const float* q_b  = (const float*)d_in[2];
    const float* k_w  = (const float*)d_in[3];
    const float* k_b  = (const float*)d_in[4];
    const float* v_w  = (const float*)d_in[5];
    const float* v_b  = (const float*)d_in[6];
    const float* o_w  = (const float*)d_in[7];
    const float* o_b  = (const float*)d_in[8];
    const float* cosp = (const float*)d_in[9];
    const float* sinp = (const float*)d_in[10];
    const int*   cu   = (const int*)d_in[11];
    float* out = (float*)d_out;

    char* p = (char*)d_ws;
    u16* hs_h = (u16*)p; p += (size_t)S * E * 2;
    u16* wq_h = (u16*)p; p += (size_t)E * E * 2;   // wq/wk/wv contiguous = Wcat[3456][1152]
    u16* wk_h = (u16*)p; p += (size_t)E * E * 2;
    u16* wv_h = (u16*)p; p += (size_t)E * E * 2;
    u16* wo_h = (u16*)p; p += (size_t)E * E * 2;
    u16* qbf = (u16*)p; p += (size_t)H * S * 96 * 2;
    u16* kbf = (u16*)p; p += (size_t)H * S * 96 * 2;
    u16* vt  = (u16*)p; p += (size_t)H * 80 * S * 2;
    u16* ao  = (u16*)p; p += (size_t)S * E * 2;

    convert_inputs<<<7488, 256, 0, stream>>>(hs, q_w, k_w, v_w, o_w,
                                             hs_h, wq_h, wk_h, wv_h, wo_h);
    dim3 gq(27, 16);
    gemm_qkv_f<<<gq, 256, 0, stream>>>(hs_h, wq_h, q_b, k_b, v_b, qbf, kbf, vt);
    rope_convert<<<(S * H * 36) / 256, 256, 0, stream>>>(qbf, kbf, cosp, sinp, vt);
    attn_mfma<<<512, 256, 0, stream>>>(qbf, kbf, vt, ao, cu);
    gemm_o<<<288, 256, 0, stream>>>(ao, wo_h, o_b, out);
}